// Round 7
// baseline (179.958 us; speedup 1.0000x reference)
//
#include <hip/hip_runtime.h>
#include <stdint.h>

// Problem constants
#define B_TOT   65536
#define IN_DIM  512
#define H0      256
#define H1      128
#define HH      64
#define NDIS    12

#define BM      32          // rows per block
#define NBLK    (B_TOT / BM)   // 2048 blocks

typedef __bf16 bf16_t;
typedef __bf16 bf16x4 __attribute__((ext_vector_type(4)));
typedef __bf16 bf16x8 __attribute__((ext_vector_type(8)));
typedef float  f32x4  __attribute__((ext_vector_type(4)));

// ---- workspace layout (bytes) ----
#define WS_W0T   0u          // bf16 [256][512]  (W0t[c][k] = W0[k][c])
#define WS_W1T   262144u     // bf16 [128][256]
#define WS_WZT   327680u     // bf16 [12][64][128] (Wzt[d][h][e] = Wz[d][e][h])
#define WS_WIT   524288u     // bf16 [16][128]  (w_init rows, zero-padded to 16)
#define WS_AL0   528384u     // f32 [256]
#define WS_BE0   529408u     // f32 [256]
#define WS_AL1   530432u     // f32 [128]
#define WS_BE1   530944u     // f32 [128]
#define WS_NEED  531456u

// ---- fused-kernel LDS (17408 B peak; 8 blocks/CU) ----
// P0 : xs dbuf 2 x [32][64] bf16 (chunk-XOR swizzle)     [0..8192)
// P1/2: hs [32][264] bf16                                [0..16896)
// P3+ : zs [32][136] bf16 @0 ; psf [32][20] f32 @8704 ;
//       part [12][32][2] f32 @11264 ; obuf 1536 B aliases psf
#define L_PS     8704u
#define L_PART   11264u
#define L_TOTAL  17408u

__device__ __forceinline__ f32x4 MF(bf16x8 a, bf16x8 b, f32x4 c) {
    return __builtin_amdgcn_mfma_f32_16x16x32_bf16(a, b, c, 0, 0, 0);
}
// Light barrier: LDS-visibility only; global prefetches stay in flight.
__device__ __forceinline__ void BAR() {
    asm volatile("s_waitcnt lgkmcnt(0)\n\ts_barrier" ::: "memory");
}

#define PACK8(o, lo, hi) { o[0]=(bf16_t)lo[0]; o[1]=(bf16_t)lo[1]; o[2]=(bf16_t)lo[2]; o[3]=(bf16_t)lo[3]; \
                           o[4]=(bf16_t)hi[0]; o[5]=(bf16_t)hi[1]; o[6]=(bf16_t)hi[2]; o[7]=(bf16_t)hi[3]; }

// =====================================================================
// Prep: transpose + f32->bf16 weights, fold BN (+bias) into alpha/beta
// =====================================================================
__global__ void prep_kernel(const float* __restrict__ W0, const float* __restrict__ b0,
                            const float* __restrict__ g0, const float* __restrict__ bb0,
                            const float* __restrict__ mm0, const float* __restrict__ vv0,
                            const float* __restrict__ W1, const float* __restrict__ b1,
                            const float* __restrict__ g1, const float* __restrict__ bb1,
                            const float* __restrict__ mm1, const float* __restrict__ vv1,
                            const float* __restrict__ w_init, const float* __restrict__ Wz,
                            char* __restrict__ ws)
{
    bf16_t* W0t = (bf16_t*)(ws + WS_W0T);
    bf16_t* W1t = (bf16_t*)(ws + WS_W1T);
    bf16_t* Wzt = (bf16_t*)(ws + WS_WZT);
    bf16_t* wiT = (bf16_t*)(ws + WS_WIT);
    float* al0 = (float*)(ws + WS_AL0);
    float* be0 = (float*)(ws + WS_BE0);
    float* al1 = (float*)(ws + WS_AL1);
    float* be1 = (float*)(ws + WS_BE1);

    int t = blockIdx.x * 256 + threadIdx.x;   // 512*256 = 131072 threads

    { // W0t: 256*512
        int c = t >> 9, k = t & 511;
        W0t[t] = (bf16_t)W0[k * H0 + c];
    }
    if (t < H1 * H0) { // W1t
        int c = t >> 8, k = t & 255;
        W1t[t] = (bf16_t)W1[k * H1 + c];
    }
    if (t < NDIS * HH * H1) { // Wzt ; Wz is [12][128][64]
        int d = t >> 13, r = t & 8191, h = r >> 7, e = r & 127;
        Wzt[t] = (bf16_t)Wz[d * 8192 + e * 64 + h];
    }
    if (t < 16 * H1) { // w_initT (pad 12->16)
        int d = t >> 7, e = t & 127;
        wiT[t] = (d < NDIS) ? (bf16_t)w_init[d * H1 + e] : (bf16_t)0.0f;
    }
    if (t < H0) {
        float a = g0[t] * rsqrtf(vv0[t] + 1e-5f);
        al0[t] = a;
        be0[t] = (b0[t] - mm0[t]) * a + bb0[t];
    }
    if (t < H1) {
        float a = g1[t] * rsqrtf(vv1[t] + 1e-5f);
        al1[t] = a;
        be1[t] = (b1[t] - mm1[t]) * a + bb1[t];
    }
}

// =====================================================================
// Fused kernel: 32 rows/block, 128 threads (2 waves), 8 blocks/CU.
// Swapped MFMA operands (A = weight rows, B = activation rows).
// =====================================================================
__global__ __launch_bounds__(128, 4) void fused_kernel(
    const float* __restrict__ x,
    const bf16_t* __restrict__ W0t, const bf16_t* __restrict__ W1t,
    const float* __restrict__ al0, const float* __restrict__ be0,
    const float* __restrict__ al1, const float* __restrict__ be1,
    const bf16_t* __restrict__ Wzt, const bf16_t* __restrict__ wiT,
    const float* __restrict__ b_init, const float* __restrict__ Wp,
    const float* __restrict__ bh, const float* __restrict__ Wo,
    const float* __restrict__ bo, const float* __restrict__ pred_w,
    const int* __restrict__ pred_idx, float* __restrict__ out)
{
    __shared__ __align__(16) char smem[L_TOTAL];

    const int tid  = threadIdx.x;
    const int lane = tid & 63, w = tid >> 6;      // 2 waves
    const int l15 = lane & 15, lg = lane >> 4;
    const int m0 = blockIdx.x * BM;

    bf16_t* xs = (bf16_t*)smem;

    // ---- P0: GEMM0 (h^T = W0t @ x-rows), BK=64, 8 steps ----
    // staging: 2 chunks/thread; chunk f: row = f>>3 (0..31), s = f&7 (16B)
    const float *sgp0, *sgp1;
    int sd0, sd1;
    {
        int f0 = tid, f1 = tid + 128;
        int r0 = f0 >> 3, s0 = f0 & 7, r1 = f1 >> 3, s1 = f1 & 7;
        sgp0 = x + (size_t)(m0 + r0) * IN_DIM + s0 * 8;
        sgp1 = x + (size_t)(m0 + r1) * IN_DIM + s1 * 8;
        sd0 = r0 * 64 + ((s0 ^ (r0 & 7)) << 3);
        sd1 = r1 * 64 + ((s1 ^ (r1 & 7)) << 3);
    }
    // wave w owns h-cols [w*128, w*128+128): 8 mf-frags
    const bf16_t* wg = W0t + (size_t)(w * 128 + l15) * IN_DIM + lg * 8;
    const int xb0 = ((lg ^ (l15 & 7)) << 3);          // kf=0 chunk (swz)
    const int xb1 = (((4 | lg) ^ (l15 & 7)) << 3);    // kf=1 chunk

    f32x4 acc[8][2] = {};    // [mf][nf]
    f32x4 lo0, hi0, lo1, hi1;

    lo0 = *(const f32x4*)(sgp0);     hi0 = *(const f32x4*)(sgp0 + 4);
    lo1 = *(const f32x4*)(sgp1);     hi1 = *(const f32x4*)(sgp1 + 4);
    { bf16x8 o; PACK8(o, lo0, hi0); *(bf16x8*)(xs + sd0) = o; }
    { bf16x8 o; PACK8(o, lo1, hi1); *(bf16x8*)(xs + sd1) = o; }
    lo0 = *(const f32x4*)(sgp0 + 64); hi0 = *(const f32x4*)(sgp0 + 68);
    lo1 = *(const f32x4*)(sgp1 + 64); hi1 = *(const f32x4*)(sgp1 + 68);
    BAR();

    #pragma unroll 1
    for (int ks = 0; ks < 8; ++ks) {
        // stage x(ks+1); prefetch x(ks+2)
        if (ks < 7) {
            bf16_t* xw = xs + ((ks + 1) & 1) * 2048;
            { bf16x8 o; PACK8(o, lo0, hi0); *(bf16x8*)(xw + sd0) = o; }
            { bf16x8 o; PACK8(o, lo1, hi1); *(bf16x8*)(xw + sd1) = o; }
            if (ks < 6) {
                lo0 = *(const f32x4*)(sgp0 + (ks + 2) * 64); hi0 = *(const f32x4*)(sgp0 + (ks + 2) * 64 + 4);
                lo1 = *(const f32x4*)(sgp1 + (ks + 2) * 64); hi1 = *(const f32x4*)(sgp1 + (ks + 2) * 64 + 4);
            }
        }
        const bf16_t* xr = xs + (ks & 1) * 2048;
        // kf = 0
        {
            bf16x8 a[8];
            #pragma unroll
            for (int mf = 0; mf < 8; ++mf)
                a[mf] = *(const bf16x8*)(wg + (size_t)mf * 16 * IN_DIM + ks * 64);
            #pragma unroll
            for (int nf = 0; nf < 2; ++nf) {
                bf16x8 b = *(const bf16x8*)(xr + (nf * 16 + l15) * 64 + xb0);
                #pragma unroll
                for (int mf = 0; mf < 8; ++mf) acc[mf][nf] = MF(a[mf], b, acc[mf][nf]);
            }
        }
        // kf = 1
        {
            bf16x8 a[8];
            #pragma unroll
            for (int mf = 0; mf < 8; ++mf)
                a[mf] = *(const bf16x8*)(wg + (size_t)mf * 16 * IN_DIM + ks * 64 + 32);
            #pragma unroll
            for (int nf = 0; nf < 2; ++nf) {
                bf16x8 b = *(const bf16x8*)(xr + (nf * 16 + l15) * 64 + xb1);
                #pragma unroll
                for (int mf = 0; mf < 8; ++mf) acc[mf][nf] = MF(a[mf], b, acc[mf][nf]);
            }
        }
        BAR();
    }

    // ---- P1: BN0 + ReLU -> hs [32][264] bf16 ----
    {
        bf16_t* hs = (bf16_t*)smem;
        #pragma unroll
        for (int mf = 0; mf < 8; ++mf) {
            int c = w * 128 + mf * 16 + lg * 4;
            f32x4 al = *(const f32x4*)(al0 + c);
            f32x4 be = *(const f32x4*)(be0 + c);
            #pragma unroll
            for (int nf = 0; nf < 2; ++nf) {
                int r = nf * 16 + l15;
                bf16x4 o;
                #pragma unroll
                for (int j = 0; j < 4; ++j)
                    o[j] = (bf16_t)fmaxf(acc[mf][nf][j] * al[j] + be[j], 0.f);
                *(bf16x4*)(hs + r * 264 + c) = o;
            }
        }
    }
    BAR();

    // ---- P2: GEMM1 (z^T = W1t @ h-rows), A 1-kf-ahead from L2, B from hs ----
    f32x4 acc2[4][2] = {};
    {
        const bf16_t* hs  = (const bf16_t*)smem;
        const bf16_t* w1g = W1t + (size_t)(w * 64 + l15) * H0 + lg * 8;
        bf16x8 aP[4], aQ[4];
        #pragma unroll
        for (int mf = 0; mf < 4; ++mf) aP[mf] = *(const bf16x8*)(w1g + (size_t)mf * 16 * H0);
        #pragma unroll
        for (int mf = 0; mf < 4; ++mf) aQ[mf] = *(const bf16x8*)(w1g + (size_t)mf * 16 * H0 + 32);
        #pragma unroll
        for (int kf = 0; kf < 8; ++kf) {
            bf16x8 ac[4];
            #pragma unroll
            for (int mf = 0; mf < 4; ++mf) ac[mf] = (kf & 1) ? aQ[mf] : aP[mf];
            if (kf < 6) {
                #pragma unroll
                for (int mf = 0; mf < 4; ++mf) {
                    bf16x8 nv = *(const bf16x8*)(w1g + (size_t)mf * 16 * H0 + (kf + 2) * 32);
                    if (kf & 1) aQ[mf] = nv; else aP[mf] = nv;
                }
            }
            #pragma unroll
            for (int nf = 0; nf < 2; ++nf) {
                bf16x8 b = *(const bf16x8*)(hs + (nf * 16 + l15) * 264 + kf * 32 + lg * 8);
                #pragma unroll
                for (int mf = 0; mf < 4; ++mf) acc2[mf][nf] = MF(ac[mf], b, acc2[mf][nf]);
            }
        }
    }
    BAR();   // all hs reads done
    {
        bf16_t* zs = (bf16_t*)smem;   // overwrite hs region
        #pragma unroll
        for (int mf = 0; mf < 4; ++mf) {
            int c = w * 64 + mf * 16 + lg * 4;
            f32x4 al = *(const f32x4*)(al1 + c);
            f32x4 be = *(const f32x4*)(be1 + c);
            #pragma unroll
            for (int nf = 0; nf < 2; ++nf) {
                int r = nf * 16 + l15;
                bf16x4 o;
                #pragma unroll
                for (int j = 0; j < 4; ++j)
                    o[j] = (bf16_t)fmaxf(acc2[mf][nf][j] * al[j] + be[j], 0.f);
                *(bf16x4*)(zs + r * 136 + c) = o;
            }
        }
    }
    BAR();

    const bf16_t* zs = (const bf16_t*)smem;
    float* psf  = (float*)(smem + L_PS);     // [32][20] f32
    float* part = (float*)(smem + L_PART);   // [12][32][2] f32

    // ---- P3: p = sigmoid(z @ w_init^T); wave w does rows w*16..+15 ----
    {
        f32x4 pacc = {};
        #pragma unroll
        for (int kf = 0; kf < 4; ++kf) {
            bf16x8 aw = *(const bf16x8*)(wiT + l15 * H1 + kf * 32 + lg * 8);
            bf16x8 bz = *(const bf16x8*)(zs + (w * 16 + l15) * 136 + kf * 32 + lg * 8);
            pacc = MF(aw, bz, pacc);
        }
        f32x4 pv;
        #pragma unroll
        for (int j = 0; j < 4; ++j) {
            int d = lg * 4 + j;
            float bi = (d < NDIS) ? b_init[d] : 0.f;
            pv[j] = 1.f / (1.f + __expf(-(pacc[j] + bi)));
        }
        *(f32x4*)(psf + (w * 16 + l15) * 20 + lg * 4) = pv;
    }
    BAR();

    // ---- P4: hoist ALL z B-frags to regs (8 frags = 32 VGPR), then 12 heads
    //      with zero LDS reads and zero barriers in the loop.
    bf16x8 zb[2][4];
    #pragma unroll
    for (int nf = 0; nf < 2; ++nf)
        #pragma unroll
        for (int kf = 0; kf < 4; ++kf)
            zb[nf][kf] = *(const bf16x8*)(zs + (nf * 16 + l15) * 136 + kf * 32 + lg * 8);

    // wave w owns h-half [w*32, w*32+32): 2 hg-frags per eg
    const bf16_t* wzg = Wzt + (size_t)(w * 32 + l15) * H1 + lg * 8;

    #pragma unroll 1
    for (int d = 0; d < NDIS; ++d) {
        const bf16_t* wd = wzg + (size_t)d * 8192;
        bf16x8 az[2][4];
        #pragma unroll
        for (int hg = 0; hg < 2; ++hg)
            #pragma unroll
            for (int eg = 0; eg < 4; ++eg)
                az[hg][eg] = *(const bf16x8*)(wd + (size_t)hg * 16 * H1 + eg * 32);

        f32x4 hacc[2][2] = {};   // [hg][nf]
        #pragma unroll
        for (int hg = 0; hg < 2; ++hg)
            #pragma unroll
            for (int eg = 0; eg < 4; ++eg)
                #pragma unroll
                for (int nf = 0; nf < 2; ++nf)
                    hacc[hg][nf] = MF(az[hg][eg], zb[nf][eg], hacc[hg][nf]);

        int i0 = pred_idx[d * 3 + 0], i1 = pred_idx[d * 3 + 1], i2 = pred_idx[d * 3 + 2];
        float wq0 = pred_w[d * 3 + 0], wq1 = pred_w[d * 3 + 1], wq2 = pred_w[d * 3 + 2];

        #pragma unroll
        for (int nf = 0; nf < 2; ++nf) {
            int r = nf * 16 + l15;
            float a0 = psf[r * 20 + i0] * wq0;
            float a1 = psf[r * 20 + i1] * wq1;
            float a2 = psf[r * 20 + i2] * wq2;
            float s = 0.f;
            #pragma unroll
            for (int hg = 0; hg < 2; ++hg) {
                int hb = w * 32 + hg * 16 + lg * 4;
                f32x4 bhv = *(const f32x4*)(bh + d * 64 + hb);
                f32x4 wov = *(const f32x4*)(Wo + d * 64 + hb);
                f32x4 wpa = *(const f32x4*)(Wp + d * 192 + hb);
                f32x4 wpb = *(const f32x4*)(Wp + d * 192 + 64 + hb);
                f32x4 wpc = *(const f32x4*)(Wp + d * 192 + 128 + hb);
                #pragma unroll
                for (int j = 0; j < 4; ++j) {
                    float v = hacc[hg][nf][j] + bhv[j] + a0 * wpa[j] + a1 * wpb[j] + a2 * wpc[j];
                    s += fmaxf(v, 0.f) * wov[j];
                }
            }
            s += __shfl_xor(s, 16);
            s += __shfl_xor(s, 32);
            if (lane < 16) part[d * 64 + r * 2 + w] = s;
        }
    }
    BAR();

    // ---- final: reduce partials, sigmoid, coalesced store ----
    {
        float* obuf = (float*)(smem + L_PS);   // aliases psf (dead)
        #pragma unroll
        for (int i = 0; i < 3; ++i) {
            int e = tid * 3 + i;               // 384 outputs = [32 rows][12 d]
            int d = e % 12, r = e / 12;
            float s = part[d * 64 + r * 2] + part[d * 64 + r * 2 + 1] + bo[d];
            obuf[e] = 1.f / (1.f + __expf(-s));
        }
    }
    BAR();
    if (tid < 96) {
        f32x4 o = *(const f32x4*)((const float*)(smem + L_PS) + tid * 4);
        *(f32x4*)(out + (size_t)blockIdx.x * 384 + tid * 4) = o;
    }
}

// =====================================================================
extern "C" void kernel_launch(void* const* d_in, const int* in_sizes, int n_in,
                              void* d_out, int out_size, void* d_ws, size_t ws_size,
                              hipStream_t stream) {
    if (ws_size < (size_t)WS_NEED) return;

    const float* x      = (const float*)d_in[0];
    const float* W0     = (const float*)d_in[1];
    const float* b0     = (const float*)d_in[2];
    const float* g0     = (const float*)d_in[3];
    const float* bb0    = (const float*)d_in[4];
    const float* mm0    = (const float*)d_in[5];
    const float* vv0    = (const float*)d_in[6];
    const float* W1     = (const float*)d_in[7];
    const float* b1     = (const float*)d_in[8];
    const float* g1     = (const float*)d_in[9];
    const float* bb1    = (const float*)d_in[10];
    const float* mm1    = (const float*)d_in[11];
    const float* vv1    = (const float*)d_in[12];
    const float* w_init = (const float*)d_in[13];
    const float* b_init = (const float*)d_in[14];
    const float* Wz     = (const float*)d_in[15];
    const float* Wp     = (const float*)d_in[16];
    const float* bh     = (const float*)d_in[17];
    const float* Wo     = (const float*)d_in[18];
    const float* bo     = (const float*)d_in[19];
    const float* pred_w = (const float*)d_in[20];
    const int*   pred_idx = (const int*)d_in[21];

    char* ws = (char*)d_ws;
    const bf16_t* W0t = (const bf16_t*)(ws + WS_W0T);
    const bf16_t* W1t = (const bf16_t*)(ws + WS_W1T);
    const bf16_t* Wzt = (const bf16_t*)(ws + WS_WZT);
    const bf16_t* wiT = (const bf16_t*)(ws + WS_WIT);
    const float* al0 = (const float*)(ws + WS_AL0);
    const float* be0 = (const float*)(ws + WS_BE0);
    const float* al1 = (const float*)(ws + WS_AL1);
    const float* be1 = (const float*)(ws + WS_BE1);

    prep_kernel<<<dim3(512), dim3(256), 0, stream>>>(
        W0, b0, g0, bb0, mm0, vv0, W1, b1, g1, bb1, mm1, vv1, w_init, Wz, ws);

    fused_kernel<<<dim3(NBLK), dim3(128), 0, stream>>>(
        x, W0t, W1t, al0, be0, al1, be1, Wzt, wiT, b_init, Wp, bh, Wo, bo,
        pred_w, pred_idx, (float*)d_out);
}

// Round 8
// 95.942 us; speedup vs baseline: 1.8757x; 1.8757x over previous
//
#include <hip/hip_runtime.h>
#include <stdint.h>

// Problem constants
#define B_TOT   65536
#define IN_DIM  512
#define H0      256
#define H1      128
#define HH      64
#define NDIS    12

#define BM      64
#define NBLK    (B_TOT / BM)   // 1024 blocks

typedef __bf16 bf16_t;
typedef __bf16 bf16x4 __attribute__((ext_vector_type(4)));
typedef __bf16 bf16x8 __attribute__((ext_vector_type(8)));
typedef float  f32x4  __attribute__((ext_vector_type(4)));

// ---- workspace layout (bytes) ----
#define WS_W0T   0u          // bf16 [256][512]  (W0t[c][k] = W0[k][c])
#define WS_W1T   262144u     // bf16 [128][256]
#define WS_WZT   327680u     // bf16 [12][64][128] (Wzt[d][h][e] = Wz[d][e][h])
#define WS_WIT   524288u     // bf16 [16][128]  (w_init rows, zero-padded to 16)
#define WS_AL0   528384u     // f32 [256]
#define WS_BE0   529408u     // f32 [256]
#define WS_AL1   530432u     // f32 [128]
#define WS_BE1   530944u     // f32 [128]
#define WS_NEED  531456u

// ---- fused-kernel LDS (49152 B; 3 blocks/CU) ----
// P0 : x ring 3 x [64 rows][16 slots of 16B] f32 (slot-XOR swizzle) [0..49152)
// P1/2: hs [64][264] bf16 @0 (aliases ring)                         [0..33792)
// P3+ : zs [64][136] bf16 @0 ; psf [64][20] f32 @17408 ;
//       part [12][64][4] f32 @22528 ; obuf 3 KB aliases psf
#define L_PS     17408u
#define L_PART   22528u
#define L_TOTAL  49152u

__device__ __forceinline__ f32x4 MF(bf16x8 a, bf16x8 b, f32x4 c) {
    return __builtin_amdgcn_mfma_f32_16x16x32_bf16(a, b, c, 0, 0, 0);
}
__device__ __forceinline__ void dma16(const void* g, void* l) {
    __builtin_amdgcn_global_load_lds(
        (const __attribute__((address_space(1))) unsigned*)g,
        (__attribute__((address_space(3))) unsigned*)l, 16, 0, 0);
}
// Light barrier: LDS visibility only; global prefetches stay in flight.
__device__ __forceinline__ void BAR() {
    asm volatile("s_waitcnt lgkmcnt(0)\ns_barrier" ::: "memory");
}
// Counted wait + barrier fused in ONE asm so nothing can be hoisted between.
#define WAITBAR(N) asm volatile("s_waitcnt vmcnt(" #N ") lgkmcnt(0)\ns_barrier" ::: "memory")

#define PACK8(o, lo, hi) { o[0]=(bf16_t)lo[0]; o[1]=(bf16_t)lo[1]; o[2]=(bf16_t)lo[2]; o[3]=(bf16_t)lo[3]; \
                           o[4]=(bf16_t)hi[0]; o[5]=(bf16_t)hi[1]; o[6]=(bf16_t)hi[2]; o[7]=(bf16_t)hi[3]; }

// =====================================================================
// Prep: transpose + f32->bf16 weights, fold BN (+bias) into alpha/beta
// =====================================================================
__global__ void prep_kernel(const float* __restrict__ W0, const float* __restrict__ b0,
                            const float* __restrict__ g0, const float* __restrict__ bb0,
                            const float* __restrict__ mm0, const float* __restrict__ vv0,
                            const float* __restrict__ W1, const float* __restrict__ b1,
                            const float* __restrict__ g1, const float* __restrict__ bb1,
                            const float* __restrict__ mm1, const float* __restrict__ vv1,
                            const float* __restrict__ w_init, const float* __restrict__ Wz,
                            char* __restrict__ ws)
{
    bf16_t* W0t = (bf16_t*)(ws + WS_W0T);
    bf16_t* W1t = (bf16_t*)(ws + WS_W1T);
    bf16_t* Wzt = (bf16_t*)(ws + WS_WZT);
    bf16_t* wiT = (bf16_t*)(ws + WS_WIT);
    float* al0 = (float*)(ws + WS_AL0);
    float* be0 = (float*)(ws + WS_BE0);
    float* al1 = (float*)(ws + WS_AL1);
    float* be1 = (float*)(ws + WS_BE1);

    int t = blockIdx.x * 256 + threadIdx.x;   // 512*256 = 131072 threads

    { // W0t: 256*512
        int c = t >> 9, k = t & 511;
        W0t[t] = (bf16_t)W0[k * H0 + c];
    }
    if (t < H1 * H0) { // W1t
        int c = t >> 8, k = t & 255;
        W1t[t] = (bf16_t)W1[k * H1 + c];
    }
    if (t < NDIS * HH * H1) { // Wzt ; Wz is [12][128][64]
        int d = t >> 13, r = t & 8191, h = r >> 7, e = r & 127;
        Wzt[t] = (bf16_t)Wz[d * 8192 + e * 64 + h];
    }
    if (t < 16 * H1) { // w_initT (pad 12->16)
        int d = t >> 7, e = t & 127;
        wiT[t] = (d < NDIS) ? (bf16_t)w_init[d * H1 + e] : (bf16_t)0.0f;
    }
    if (t < H0) {
        float a = g0[t] * rsqrtf(vv0[t] + 1e-5f);
        al0[t] = a;
        be0[t] = (b0[t] - mm0[t]) * a + bb0[t];
    }
    if (t < H1) {
        float a = g1[t] * rsqrtf(vv1[t] + 1e-5f);
        al1[t] = a;
        be1[t] = (b1[t] - mm1[t]) * a + bb1[t];
    }
}

// =====================================================================
// Fused kernel: 64 rows/block, 256 threads (4 waves), 3 blocks/CU.
// P0: 3-deep global_load_lds ring with counted vmcnt (never drains);
// A-frags (weights) register-double-buffered one step ahead.
// =====================================================================
__global__ __launch_bounds__(256, 3) void fused_kernel(
    const float* __restrict__ x,
    const bf16_t* __restrict__ W0t, const bf16_t* __restrict__ W1t,
    const float* __restrict__ al0, const float* __restrict__ be0,
    const float* __restrict__ al1, const float* __restrict__ be1,
    const bf16_t* __restrict__ Wzt, const bf16_t* __restrict__ wiT,
    const float* __restrict__ b_init, const float* __restrict__ Wp,
    const float* __restrict__ bh, const float* __restrict__ Wo,
    const float* __restrict__ bo, const float* __restrict__ pred_w,
    const int* __restrict__ pred_idx, float* __restrict__ out)
{
    __shared__ __align__(16) char smem[L_TOTAL];

    const int tid  = threadIdx.x;
    const int lane = tid & 63, w = tid >> 6;      // 4 waves
    const int l15 = lane & 15, lg = lane >> 4;
    const int m0 = blockIdx.x * BM;

    // ---------------- P0: GEMM0 (h^T = W0t @ x-rows), BK=64, 8 steps -------
    // DMA: wave w stages rows [w*16, w*16+16). Per step: 4 dma16/wave.
    // LDS phys slot p holds global slot p ^ (row&15) (pre-swizzled source).
    const float* xsrc[4];
    float* xdst[4];
    #pragma unroll
    for (int i = 0; i < 4; ++i) {
        int row = w * 16 + i * 4 + (lane >> 4);
        int gslot = (lane & 15) ^ (row & 15);
        xsrc[i] = x + (size_t)(m0 + row) * IN_DIM + gslot * 4;
        xdst[i] = (float*)smem + (w * 16 + i * 4) * 64;   // wave-uniform
    }
    const bf16_t* wg = W0t + (size_t)(w * 64 + l15) * IN_DIM + lg * 8;

    f32x4 acc[4][4] = {};
    bf16x8 aA[2][4], aB[2][4];

#define ISSUE_DMA(K) { _Pragma("unroll") \
    for (int i = 0; i < 4; ++i) dma16(xsrc[i] + (K) * 64, xdst[i] + ((K) % 3) * 4096); }
#define ISSUE_A(K, SET) { _Pragma("unroll") \
    for (int mf = 0; mf < 4; ++mf) { \
        SET[0][mf] = *(const bf16x8*)(wg + (size_t)mf * 16 * IN_DIM + (K) * 64); \
        SET[1][mf] = *(const bf16x8*)(wg + (size_t)mf * 16 * IN_DIM + (K) * 64 + 32); } }
#define MFMA_STEP(K, CUR) { \
    const float* xb = (const float*)smem + ((K) % 3) * 1024 * 4; \
    __builtin_amdgcn_s_setprio(1); \
    _Pragma("unroll") \
    for (int kf = 0; kf < 2; ++kf) { \
        _Pragma("unroll") \
        for (int nf = 0; nf < 4; ++nf) { \
            int s0 = kf * 8 + lg * 2; \
            f32x4 u = *(const f32x4*)(xb + (nf * 16 + l15) * 64 + ((s0    ) ^ l15) * 4); \
            f32x4 v = *(const f32x4*)(xb + (nf * 16 + l15) * 64 + ((s0 + 1) ^ l15) * 4); \
            bf16x8 b; PACK8(b, u, v); \
            _Pragma("unroll") \
            for (int mf = 0; mf < 4; ++mf) acc[mf][nf] = MF(CUR[kf][mf], b, acc[mf][nf]); \
        } \
    } \
    __builtin_amdgcn_s_setprio(0); }

    // prologue: D0, A0, D1 in flight (16 vm-ops)
    ISSUE_DMA(0);
    ISSUE_A(0, aA);
    ISSUE_DMA(1);

    // steps 0..5: wait vmcnt(12) [this step's 4 DMAs done], barrier,
    // issue D(k+2) + A(k+1), then MFMA from ring buf k%3.
    WAITBAR(12); ISSUE_DMA(2); ISSUE_A(1, aB); MFMA_STEP(0, aA);
    WAITBAR(12); ISSUE_DMA(3); ISSUE_A(2, aA); MFMA_STEP(1, aB);
    WAITBAR(12); ISSUE_DMA(4); ISSUE_A(3, aB); MFMA_STEP(2, aA);
    WAITBAR(12); ISSUE_DMA(5); ISSUE_A(4, aA); MFMA_STEP(3, aB);
    WAITBAR(12); ISSUE_DMA(6); ISSUE_A(5, aB); MFMA_STEP(4, aA);
    WAITBAR(12); ISSUE_DMA(7); ISSUE_A(6, aA); MFMA_STEP(5, aB);
    WAITBAR(12);               ISSUE_A(7, aB); MFMA_STEP(6, aA);
    WAITBAR(8);                                MFMA_STEP(7, aB);

    // drain everything before overwriting the ring with hs
    asm volatile("s_waitcnt vmcnt(0) lgkmcnt(0)\ns_barrier" ::: "memory");

    // ---------------- P1: BN0 + ReLU -> hs [64][264] bf16 ----------------
    {
        bf16_t* hs = (bf16_t*)smem;
        #pragma unroll
        for (int mf = 0; mf < 4; ++mf) {
            int c = w * 64 + mf * 16 + lg * 4;
            f32x4 al = *(const f32x4*)(al0 + c);
            f32x4 be = *(const f32x4*)(be0 + c);
            #pragma unroll
            for (int nf = 0; nf < 4; ++nf) {
                int r = nf * 16 + l15;
                bf16x4 o;
                #pragma unroll
                for (int j = 0; j < 4; ++j)
                    o[j] = (bf16_t)fmaxf(acc[mf][nf][j] * al[j] + be[j], 0.f);
                *(bf16x4*)(hs + r * 264 + c) = o;
            }
        }
    }
    BAR();

    // ---------------- P2: GEMM1 (z^T = W1t @ h-rows) ----------------
    f32x4 acc2[2][4] = {};
    {
        const bf16_t* hs  = (const bf16_t*)smem;
        const bf16_t* w1g = W1t + (size_t)(w * 32 + l15) * H0 + lg * 8;
        bf16x8 aP[2], aQ[2];
        aP[0] = *(const bf16x8*)(w1g);
        aP[1] = *(const bf16x8*)(w1g + 16 * H0);
        aQ[0] = *(const bf16x8*)(w1g + 32);
        aQ[1] = *(const bf16x8*)(w1g + 16 * H0 + 32);
        #pragma unroll
        for (int kf = 0; kf < 8; ++kf) {
            bf16x8 ac0 = (kf & 1) ? aQ[0] : aP[0];
            bf16x8 ac1 = (kf & 1) ? aQ[1] : aP[1];
            if (kf < 6) {
                if (kf & 1) {
                    aQ[0] = *(const bf16x8*)(w1g + (kf + 2) * 32);
                    aQ[1] = *(const bf16x8*)(w1g + 16 * H0 + (kf + 2) * 32);
                } else {
                    aP[0] = *(const bf16x8*)(w1g + (kf + 2) * 32);
                    aP[1] = *(const bf16x8*)(w1g + 16 * H0 + (kf + 2) * 32);
                }
            }
            #pragma unroll
            for (int nf = 0; nf < 4; ++nf) {
                bf16x8 b = *(const bf16x8*)(hs + (nf * 16 + l15) * 264 + kf * 32 + lg * 8);
                acc2[0][nf] = MF(ac0, b, acc2[0][nf]);
                acc2[1][nf] = MF(ac1, b, acc2[1][nf]);
            }
        }
    }
    BAR();   // all hs reads done
    {
        bf16_t* zs = (bf16_t*)smem;   // overwrite hs region
        #pragma unroll
        for (int mf = 0; mf < 2; ++mf) {
            int c = w * 32 + mf * 16 + lg * 4;
            f32x4 al = *(const f32x4*)(al1 + c);
            f32x4 be = *(const f32x4*)(be1 + c);
            #pragma unroll
            for (int nf = 0; nf < 4; ++nf) {
                int r = nf * 16 + l15;
                bf16x4 o;
                #pragma unroll
                for (int j = 0; j < 4; ++j)
                    o[j] = (bf16_t)fmaxf(acc2[mf][nf][j] * al[j] + be[j], 0.f);
                *(bf16x4*)(zs + r * 136 + c) = o;
            }
        }
    }
    BAR();

    const bf16_t* zs = (const bf16_t*)smem;
    float* psf  = (float*)(smem + L_PS);     // [64][20] f32
    float* part = (float*)(smem + L_PART);   // [12][64][4] f32
    const bf16_t* wzg = Wzt + (size_t)(w * 16 + l15) * H1 + lg * 8;
    const int hb = w * 16 + lg * 4;

    // prefetch d=0 head A-frags AND epilogue constants (covers P3 latency)
    bf16x8 az0 = *(const bf16x8*)(wzg);
    bf16x8 az1 = *(const bf16x8*)(wzg + 32);
    bf16x8 az2 = *(const bf16x8*)(wzg + 64);
    bf16x8 az3 = *(const bf16x8*)(wzg + 96);
    int   ci0 = pred_idx[0], ci1 = pred_idx[1], ci2 = pred_idx[2];
    float cq0 = pred_w[0],  cq1 = pred_w[1],  cq2 = pred_w[2];
    f32x4 cbh = *(const f32x4*)(bh + hb);
    f32x4 cwo = *(const f32x4*)(Wo + hb);
    f32x4 cpa = *(const f32x4*)(Wp + hb);
    f32x4 cpb = *(const f32x4*)(Wp + 64 + hb);
    f32x4 cpc = *(const f32x4*)(Wp + 128 + hb);

    // ---------------- P3: p = sigmoid(z @ w_init^T) ----------------
    {
        f32x4 pacc = {};
        #pragma unroll
        for (int kf = 0; kf < 4; ++kf) {
            bf16x8 aw = *(const bf16x8*)(wiT + l15 * H1 + kf * 32 + lg * 8);
            bf16x8 bz = *(const bf16x8*)(zs + (w * 16 + l15) * 136 + kf * 32 + lg * 8);
            pacc = MF(aw, bz, pacc);
        }
        f32x4 pv;
        #pragma unroll
        for (int j = 0; j < 4; ++j) {
            int d = lg * 4 + j;
            float bi = (d < NDIS) ? b_init[d] : 0.f;
            pv[j] = 1.f / (1.f + __expf(-(pacc[j] + bi)));
        }
        *(f32x4*)(psf + (w * 16 + l15) * 20 + lg * 4) = pv;
    }
    BAR();

    // ---------------- P4: 12 heads, everything prefetched 1 d ahead --------
    #pragma unroll 1
    for (int d = 0; d < NDIS; ++d) {
        bf16x8 an0 = az0, an1 = az1, an2 = az2, an3 = az3;
        int   ni0 = ci0, ni1 = ci1, ni2 = ci2;
        float nq0 = cq0, nq1 = cq1, nq2 = cq2;
        f32x4 nbh = cbh, nwo = cwo, npa = cpa, npb = cpb, npc = cpc;
        if (d < NDIS - 1) {
            const bf16_t* p = wzg + (size_t)(d + 1) * 8192;
            an0 = *(const bf16x8*)(p);      an1 = *(const bf16x8*)(p + 32);
            an2 = *(const bf16x8*)(p + 64); an3 = *(const bf16x8*)(p + 96);
            ni0 = pred_idx[(d + 1) * 3]; ni1 = pred_idx[(d + 1) * 3 + 1]; ni2 = pred_idx[(d + 1) * 3 + 2];
            nq0 = pred_w[(d + 1) * 3];   nq1 = pred_w[(d + 1) * 3 + 1];   nq2 = pred_w[(d + 1) * 3 + 2];
            nbh = *(const f32x4*)(bh + (d + 1) * 64 + hb);
            nwo = *(const f32x4*)(Wo + (d + 1) * 64 + hb);
            npa = *(const f32x4*)(Wp + (d + 1) * 192 + hb);
            npb = *(const f32x4*)(Wp + (d + 1) * 192 + 64 + hb);
            npc = *(const f32x4*)(Wp + (d + 1) * 192 + 128 + hb);
        }

        #pragma unroll
        for (int nf = 0; nf < 4; ++nf) {
            const bf16_t* zr = zs + (nf * 16 + l15) * 136 + lg * 8;
            f32x4 hacc = {};
            hacc = MF(az0, *(const bf16x8*)(zr),      hacc);
            hacc = MF(az1, *(const bf16x8*)(zr + 32), hacc);
            hacc = MF(az2, *(const bf16x8*)(zr + 64), hacc);
            hacc = MF(az3, *(const bf16x8*)(zr + 96), hacc);
            int r = nf * 16 + l15;
            float a0 = psf[r * 20 + ci0] * cq0;
            float a1 = psf[r * 20 + ci1] * cq1;
            float a2 = psf[r * 20 + ci2] * cq2;
            float s = 0.f;
            #pragma unroll
            for (int j = 0; j < 4; ++j) {
                float v = hacc[j] + cbh[j] + a0 * cpa[j] + a1 * cpb[j] + a2 * cpc[j];
                s += fmaxf(v, 0.f) * cwo[j];
            }
            s += __shfl_xor(s, 16);
            s += __shfl_xor(s, 32);
            if (lane < 16) part[d * 256 + r * 4 + w] = s;
        }
        az0 = an0; az1 = an1; az2 = an2; az3 = an3;
        ci0 = ni0; ci1 = ni1; ci2 = ni2;
        cq0 = nq0; cq1 = nq1; cq2 = nq2;
        cbh = nbh; cwo = nwo; cpa = npa; cpb = npb; cpc = npc;
    }
    BAR();

    // ---------------- final: reduce partials, sigmoid, coalesced store -----
    {
        float* obuf = (float*)(smem + L_PS);   // aliases psf (dead)
        #pragma unroll
        for (int i = 0; i < 3; ++i) {
            int e = tid * 3 + i;               // 768 outputs = [64 rows][12 d]
            int d = e % 12, r = e / 12;
            f32x4 p = *(const f32x4*)(part + d * 256 + r * 4);
            float s = p[0] + p[1] + p[2] + p[3] + bo[d];
            obuf[e] = 1.f / (1.f + __expf(-s));
        }
    }
    BAR();
    if (tid < 192) {
        f32x4 o = *(const f32x4*)((const float*)(smem + L_PS) + tid * 4);
        *(f32x4*)(out + (size_t)blockIdx.x * 768 + tid * 4) = o;
    }
}

// =====================================================================
extern "C" void kernel_launch(void* const* d_in, const int* in_sizes, int n_in,
                              void* d_out, int out_size, void* d_ws, size_t ws_size,
                              hipStream_t stream) {
    if (ws_size < (size_t)WS_NEED) return;

    const float* x      = (const float*)d_in[0];
    const float* W0     = (const float*)d_in[1];
    const float* b0     = (const float*)d_in[2];
    const float* g0     = (const float*)d_in[3];
    const float* bb0    = (const float*)d_in[4];
    const float* mm0    = (const float*)d_in[5];
    const float* vv0    = (const float*)d_in[6];
    const float* W1     = (const float*)d_in[7];
    const float* b1     = (const float*)d_in[8];
    const float* g1     = (const float*)d_in[9];
    const float* bb1    = (const float*)d_in[10];
    const float* mm1    = (const float*)d_in[11];
    const float* vv1    = (const float*)d_in[12];
    const float* w_init = (const float*)d_in[13];
    const float* b_init = (const float*)d_in[14];
    const float* Wz     = (const float*)d_in[15];
    const float* Wp     = (const float*)d_in[16];
    const float* bh     = (const float*)d_in[17];
    const float* Wo     = (const float*)d_in[18];
    const float* bo     = (const float*)d_in[19];
    const float* pred_w = (const float*)d_in[20];
    const int*   pred_idx = (const int*)d_in[21];

    char* ws = (char*)d_ws;
    const bf16_t* W0t = (const bf16_t*)(ws + WS_W0T);
    const bf16_t* W1t = (const bf16_t*)(ws + WS_W1T);
    const bf16_t* Wzt = (const bf16_t*)(ws + WS_WZT);
    const bf16_t* wiT = (const bf16_t*)(ws + WS_WIT);
    const float* al0 = (const float*)(ws + WS_AL0);
    const float* be0 = (const float*)(ws + WS_BE0);
    const float* al1 = (const float*)(ws + WS_AL1);
    const float* be1 = (const float*)(ws + WS_BE1);

    prep_kernel<<<dim3(512), dim3(256), 0, stream>>>(
        W0, b0, g0, bb0, mm0, vv0, W1, b1, g1, bb1, mm1, vv1, w_init, Wz, ws);

    fused_kernel<<<dim3(NBLK), dim3(256), 0, stream>>>(
        x, W0t, W1t, al0, be0, al1, be1, Wzt, wiT, b_init, Wp, bh, Wo, bo,
        pred_w, pred_idx, (float*)d_out);
}